// Round 4
// baseline (750.805 us; speedup 1.0000x reference)
//
#include <hip/hip_runtime.h>
#include <hip/hip_bf16.h>

// Problem constants
#define KCODES 2048
#define DIM 256
#define TLEN 2048
#define NB 16
#define NROWS (NB * TLEN)          // 32768 rows (b*t)
#define NELEM (NB * DIM * TLEN)    // 8388608 elements of x / quant
#define LOSS_OFF NELEM
#define IDX_OFF (NELEM + 2)

// Approx filter margin (R8 analysis: requirement is s_approx(n*) - min_n s_approx(n)
// <= MARGIN, ~50-sigma safety for the single bf16 hi*hi sweep). Online shared-prefix
// threshold keeps the superset property: any rmin snapshot >= final global min, and
// s(n*) <= gmin + MARGIN => n* appends at its own tile.
#define MARGIN 3e-3f

// Candidate list capacity per row. Online shared-prefix E[#cands] ~ 10-20;
// overflow handled exactly by full-scan fallback in recheck.
#define CCAP 48

// ws layout (bytes) — total ~8.0 MB
#define OFF_XSQ   0ull                       // 131072 (fallback path only)
#define OFF_ESQ   131072ull                  // 8192
#define OFF_KEYS  139264ull                  // 262144
#define OFF_BSUM  401408ull                  // 131072
#define OFF_EHI   532480ull                  // 1048576
#define OFF_CCNT  1581056ull                 // 131072
#define OFF_CLIST 1712128ull                 // 32768*48*4 = 6291456
#define WS_NEED   8003584ull

typedef __bf16 bf16x8 __attribute__((ext_vector_type(8)));
typedef float  f32x4  __attribute__((ext_vector_type(4)));

__device__ __forceinline__ float sq_rn(float v) { return __fmul_rn(v, v); }

// order-preserving float<->u32 encoding (uint min == float min)
__device__ __forceinline__ unsigned encf(float f) {
    unsigned u = __float_as_uint(f);
    return (u & 0x80000000u) ? ~u : (u | 0x80000000u);
}
__device__ __forceinline__ float decf(unsigned k) {
    return __uint_as_float((k & 0x80000000u) ? (k & 0x7FFFFFFFu) : ~k);
}

// ---- x_sq: numpy pairwise sum (8-acc/128-block) — bit-exact vs np
// (fallback path only; main path computes xs inside recheck)
__global__ __launch_bounds__(256) void xsq_kernel(const float* __restrict__ x,
                                                  float* __restrict__ xsq) {
    int m = blockIdx.x * 256 + threadIdx.x;
    int b = m >> 11, t = m & (TLEN - 1);
    const float* p = x + (size_t)b * DIM * TLEN + t;
    float h[2];
#pragma unroll
    for (int half = 0; half < 2; ++half) {
        int c0 = half * 128;
        float r[8];
#pragma unroll
        for (int j = 0; j < 8; ++j) r[j] = sq_rn(p[(size_t)(c0 + j) * TLEN]);
        for (int i = 8; i < 128; i += 8) {
#pragma unroll
            for (int j = 0; j < 8; ++j)
                r[j] = __fadd_rn(r[j], sq_rn(p[(size_t)(c0 + i + j) * TLEN]));
        }
        h[half] = __fadd_rn(__fadd_rn(__fadd_rn(r[0], r[1]), __fadd_rn(r[2], r[3])),
                            __fadd_rn(__fadd_rn(r[4], r[5]), __fadd_rn(r[6], r[7])));
    }
    xsq[m] = __fadd_rn(h[0], h[1]);
}

// ---- esq standalone (fallback path only)
__global__ __launch_bounds__(256) void esq_kernel(const float* __restrict__ cb,
                                                  float* __restrict__ esq) {
    int k = blockIdx.x * 256 + threadIdx.x;
    const float* p = cb + (size_t)k * DIM;
    float h[2];
#pragma unroll
    for (int half = 0; half < 2; ++half) {
        int c0 = half * 128;
        float r[8];
#pragma unroll
        for (int j = 0; j < 8; ++j) r[j] = sq_rn(p[c0 + j]);
        for (int i = 8; i < 128; i += 8) {
#pragma unroll
            for (int j = 0; j < 8; ++j)
                r[j] = __fadd_rn(r[j], sq_rn(p[c0 + i + j]));
        }
        h[half] = __fadd_rn(__fadd_rn(__fadd_rn(r[0], r[1]), __fadd_rn(r[2], r[3])),
                            __fadd_rn(__fadd_rn(r[4], r[5]), __fadd_rn(r[6], r[7])));
    }
    esq[k] = __fadd_rn(h[0], h[1]);
}

// ---- fused prep: cb -> Ehi (bf16) + esq, one wave per code row.
// esq uses the EXACT np pairwise chain: serial r[j] accumulators (lane j of 16)
// + xor-shfl tree reproducing ((r0+r1)+(r2+r3))+((r4+r5)+(r6+r7)), halves added
// own-first -> bit-identical to esq_kernel.
__global__ __launch_bounds__(256) void prep_e_kernel(const float* __restrict__ cb,
                                                     __hip_bfloat16* __restrict__ Ehi,
                                                     float* __restrict__ esq) {
    int tid = threadIdx.x;
    int w = tid >> 6, lane = tid & 63;
    int k = (blockIdx.x << 2) + w;          // code row
    const float* p = cb + (size_t)k * DIM;

    float4 v = *reinterpret_cast<const float4*>(p + (lane << 2));
    alignas(8) __hip_bfloat16 h4[4];
    h4[0] = __float2bfloat16(v.x); h4[1] = __float2bfloat16(v.y);
    h4[2] = __float2bfloat16(v.z); h4[3] = __float2bfloat16(v.w);
    *reinterpret_cast<int2*>(Ehi + (size_t)k * DIM + (lane << 2)) = *reinterpret_cast<int2*>(h4);

    if (lane < 16) {
        int c0 = (lane >> 3) << 7, j = lane & 7;
        float r = sq_rn(p[c0 + j]);
        for (int i = 8; i < 128; i += 8)
            r = __fadd_rn(r, sq_rn(p[c0 + i + j]));
        float a  = __fadd_rn(r,  __shfl_xor(r, 1, 16));
        float b2 = __fadd_rn(a,  __shfl_xor(a, 2, 16));
        float h  = __fadd_rn(b2, __shfl_xor(b2, 4, 16));
        float tot = __fadd_rn(h, __shfl_xor(h, 8, 16));   // h0 + h1, own-first
        if (lane == 0) esq[k] = tot;
    }
}

// ---- stage one [128 codes][64 k] bf16 chunk of Ehi into LDS via global_load_lds,
// pre-swizzled-source XOR pattern (read side XORs (c&7)<<4). Wave w stages (and
// later reads) ONLY rows w*32..w*32+31 -> no cross-wave LDS hazards.
__device__ __forceinline__ void stage_chunk(const __hip_bfloat16* __restrict__ Ehi,
                                            __hip_bfloat16* dstbase,
                                            int s, int w, int srow, int scol) {
    int nt = s >> 2, kc = (s & 3) << 6;
    const __hip_bfloat16* gsrc =
        Ehi + (size_t)((nt << 7) + (w << 5) + srow) * DIM + kc + scol;
#pragma unroll
    for (int j = 0; j < 4; ++j)
        __builtin_amdgcn_global_load_lds(
            (const __attribute__((address_space(1))) unsigned int*)(gsrc + (size_t)(j << 3) * DIM),
            (__attribute__((address_space(3))) unsigned int*)(dstbase + (((w << 5) + (j << 3)) << 6)),
            16, 0, 0);
}

// ---- Phase A: 64 rows/block, loop over ALL 2048 codes. Barrier-free main loop
// (each wave reads only its own staged LDS rows), 2-buffer counted-vmcnt(4)
// pipeline with lgkmcnt(0) write-guard. ONLINE candidate filter: block-shared
// per-row running min in LDS (rmin_s, 256B); threshold = min(tile_min,
// rmin_snapshot) + MARGIN. Superset-exact (see MARGIN comment). LDS 52.5KB ->
// 3 blocks/CU (was 72.5KB/2 blocks), no 256B-stride scratch -> no conflicts.
__global__ __launch_bounds__(256, 3) void dist_cand_kernel(const float* __restrict__ x,
                                                           const __hip_bfloat16* __restrict__ Ehi,
                                                           const float* __restrict__ esq,
                                                           int* __restrict__ ccnt_g,
                                                           int* __restrict__ clist_g) {
    __shared__ __hip_bfloat16 Bh[2][128 * 64];   // 32 KB, swizzled code tiles
    __shared__ float esq_s[KCODES];              // 8 KB
    __shared__ int clist_s[64][CCAP];            // 12 KB
    __shared__ int ccnt_s[64];                   // 256 B
    __shared__ unsigned rmin_s[64];              // 256 B

    int tid = threadIdx.x;
    int w = tid >> 6, lane = tid & 63;
    int q = lane >> 4, c = lane & 15;
    int swzc = (c & 7) << 4;
    int blk = blockIdx.x;                         // 512 blocks, 64 rows each
    int b = blk >> 5;
    int t0 = (blk << 6) & (TLEN - 1);
    const float* xb = x + (size_t)b * DIM * TLEN + t0;

    // esq -> LDS (epilogue reads become lgkm-only; keeps loop vmcnt clean)
#pragma unroll
    for (int i = 0; i < 8; ++i) esq_s[tid + i * 256] = esq[tid + i * 256];
    if (tid < 64) { ccnt_s[tid] = 0; rmin_s[tid] = 0xFF7FFFFFu; }  // enc(+maxfloat)

    // A-frags: xf[mi][kh]: row t0 + mi*16 + c, k = kh*32 + q*8 + j
    bf16x8 xf[4][8];
#pragma unroll
    for (int mi = 0; mi < 4; ++mi) {
        int t = (mi << 4) + c;
#pragma unroll
        for (int kh = 0; kh < 8; ++kh) {
            alignas(16) __hip_bfloat16 h8[8];
#pragma unroll
            for (int j = 0; j < 8; ++j)
                h8[j] = __float2bfloat16(xb[(size_t)((kh << 5) + (q << 3) + j) * TLEN + t]);
            xf[mi][kh] = *reinterpret_cast<bf16x8*>(h8);
        }
    }

    f32x4 acc[2][4];
#pragma unroll
    for (int ci = 0; ci < 2; ++ci)
#pragma unroll
        for (int mi = 0; mi < 4; ++mi) acc[ci][mi] = (f32x4){0.f, 0.f, 0.f, 0.f};

    int srow = lane >> 3;
    int scol = ((lane & 7) ^ srow) << 3;

    // full drain (compiler emits vmcnt(0) lgkmcnt(0) before s_barrier): A-loads
    // and LDS inits settled -> in-loop vmcnt counts ONLY stage loads (4/chunk).
    __syncthreads();

    stage_chunk(Ehi, &Bh[0][0], 0, w, srow, scol);

    int cur = 0;
#pragma unroll 1
    for (int nt = 0; nt < 16; ++nt) {
#pragma unroll
        for (int kc = 0; kc < 4; ++kc) {
            int s = (nt << 2) + kc;
            // guard: my ds_reads from the buffer about to be overwritten are done
            asm volatile("s_waitcnt lgkmcnt(0)" ::: "memory");
            if (s < 63) stage_chunk(Ehi, &Bh[cur ^ 1][0], s + 1, w, srow, scol);
            if (s == 63) asm volatile("s_waitcnt vmcnt(0)" ::: "memory");
            else         asm volatile("s_waitcnt vmcnt(4)" ::: "memory");

            const char* basep = reinterpret_cast<const char*>(&Bh[cur][0]);
#pragma unroll
            for (int kh = 0; kh < 2; ++kh) {
                int swz = ((kh << 6) | (q << 4)) ^ swzc;
                bf16x8 cf0 = *reinterpret_cast<const bf16x8*>(basep + ((((w << 5) + c) << 7) + swz));
                bf16x8 cf1 = *reinterpret_cast<const bf16x8*>(basep + ((((w << 5) + 16 + c) << 7) + swz));
#pragma unroll
                for (int mi = 0; mi < 4; ++mi) {
                    acc[0][mi] = __builtin_amdgcn_mfma_f32_16x16x32_bf16(cf0, xf[mi][(kc << 1) | kh], acc[0][mi], 0, 0, 0);
                    acc[1][mi] = __builtin_amdgcn_mfma_f32_16x16x32_bf16(cf1, xf[mi][(kc << 1) | kh], acc[1][mi], 0, 0, 0);
                }
            }
            cur ^= 1;
        }

        // per-nt epilogue: s = esq - 2*acc (row-constant xsq cancels in all
        // comparisons). Online filter vs block-shared running min.
        float ev[8];
#pragma unroll
        for (int ci = 0; ci < 2; ++ci)
#pragma unroll
            for (int reg = 0; reg < 4; ++reg)
                ev[ci * 4 + reg] = esq_s[(nt << 7) + (w << 5) + (ci << 4) + (q << 2) + reg];

#pragma unroll
        for (int mi = 0; mi < 4; ++mi) {
            int r = (mi << 4) + c;
            float s8[8];
#pragma unroll
            for (int ci = 0; ci < 2; ++ci)
#pragma unroll
                for (int reg = 0; reg < 4; ++reg)
                    s8[ci * 4 + reg] = fmaf(-2.0f, acc[ci][mi][reg], ev[ci * 4 + reg]);
            float t01 = fminf(fminf(s8[0], s8[1]), fminf(s8[2], s8[3]));
            float t23 = fminf(fminf(s8[4], s8[5]), fminf(s8[6], s8[7]));
            float wmin = fminf(t01, t23);
            wmin = fminf(wmin, __shfl_xor(wmin, 16, 64));
            wmin = fminf(wmin, __shfl_xor(wmin, 32, 64));
            float rs = decf(rmin_s[r]);                    // snapshot (>= final gmin)
            float thr = fminf(wmin, rs) + MARGIN;
#pragma unroll
            for (int v = 0; v < 8; ++v) {
                if (s8[v] <= thr) {
                    int n = (nt << 7) + (w << 5) + ((v >> 2) << 4) + (q << 2) + (v & 3);
                    int pos = atomicAdd(&ccnt_s[r], 1);
                    if (pos < CCAP) clist_s[r][pos] = n;
                }
            }
            if (q == 0) atomicMin(&rmin_s[r], encf(wmin));
            acc[0][mi] = (f32x4){0.f, 0.f, 0.f, 0.f};
            acc[1][mi] = (f32x4){0.f, 0.f, 0.f, 0.f};
        }
    }

    __syncthreads();
    {
        int r = tid >> 2, j4 = tid & 3;
        int cnt = ccnt_s[r];
        int m = (blk << 6) + r;
        if (j4 == 0) ccnt_g[m] = cnt;               // raw count (overflow detect)
        int cl = cnt > CCAP ? CCAP : cnt;
        for (int j = j4; j < cl; j += 4)
            clist_g[(size_t)m * CCAP + j] = clist_s[r][j];
    }
}

// ---- Phase B: exact recheck over candidate lists. xs computed internally from
// the staged xT tile with the EXACT np pairwise chain. Full-scan fallback on
// overflow keeps exactness unconditional.
__global__ __launch_bounds__(256) void recheck_kernel(const float* __restrict__ x,
                                                      const float* __restrict__ cb,
                                                      const float* __restrict__ esq,
                                                      const int* __restrict__ ccnt,
                                                      const int* __restrict__ clist,
                                                      unsigned long long* __restrict__ keys) {
    __shared__ float xT[DIM * 33];

    int tid = threadIdx.x;
    int blk = blockIdx.x;               // 1024 blocks, 32 rows each
    int b = blk >> 6, t0 = (blk & 63) << 5;
    const float* xb = x + (size_t)b * DIM * TLEN + t0;

    {   // coalesced staging: 8 c-rows x 32 t per iter
        int tl = tid & 31, c8 = tid >> 5;
        for (int cc = 0; cc < 32; ++cc) {
            int c = (cc << 3) + c8;
            xT[c * 33 + tl] = xb[(size_t)c * TLEN + tl];
        }
    }
    __syncthreads();

    int g = tid >> 3, l3 = tid & 7;     // group g handles row t0+g
    int m = (b << 11) + t0 + g;

    // xs: np pairwise chain, bit-exact (lane l3 owns accumulator r[l3])
    float h[2];
#pragma unroll
    for (int half = 0; half < 2; ++half) {
        int c0 = half * 128;
        float r = sq_rn(xT[(c0 + l3) * 33 + g]);
        for (int i = 8; i < 128; i += 8)
            r = __fadd_rn(r, sq_rn(xT[(c0 + i + l3) * 33 + g]));
        float a = __fadd_rn(r, __shfl_xor(r, 1, 8));
        float bb = __fadd_rn(a, __shfl_xor(a, 2, 8));
        h[half] = __fadd_rn(bb, __shfl_xor(bb, 4, 8));
    }
    float xs = __fadd_rn(h[0], h[1]);

    int cnt = ccnt[m];
    float bd = 3.4e38f; int bi = 0x7fffffff;

    if (cnt <= CCAP) {
        for (int j = l3; j < cnt; j += 8) {
            int n = clist[(size_t)m * CCAP + j];
            const float* crow = cb + (size_t)n * DIM;
            float d = 0.f;
            for (int k = 0; k < DIM; k += 4) {     // ascending-k fmaf chain == np mm
                float4 cv = *reinterpret_cast<const float4*>(crow + k);
                d = fmaf(xT[(k + 0) * 33 + g], cv.x, d);
                d = fmaf(xT[(k + 1) * 33 + g], cv.y, d);
                d = fmaf(xT[(k + 2) * 33 + g], cv.z, d);
                d = fmaf(xT[(k + 3) * 33 + g], cv.w, d);
            }
            float d2 = __fadd_rn(__fadd_rn(xs, -2.0f * d), esq[n]);
            if (d2 < bd || (d2 == bd && n < bi)) { bd = d2; bi = n; }
        }
    } else {
        // overflow fallback: exact full scan (same formula, any order is fine)
        for (int n = l3; n < KCODES; n += 8) {
            const float* crow = cb + (size_t)n * DIM;
            float d = 0.f;
            for (int k = 0; k < DIM; k += 4) {
                float4 cv = *reinterpret_cast<const float4*>(crow + k);
                d = fmaf(xT[(k + 0) * 33 + g], cv.x, d);
                d = fmaf(xT[(k + 1) * 33 + g], cv.y, d);
                d = fmaf(xT[(k + 2) * 33 + g], cv.z, d);
                d = fmaf(xT[(k + 3) * 33 + g], cv.w, d);
            }
            float d2 = __fadd_rn(__fadd_rn(xs, -2.0f * d), esq[n]);
            if (d2 < bd || (d2 == bd && n < bi)) { bd = d2; bi = n; }
        }
    }
    for (int off = 1; off < 8; off <<= 1) {
        float od = __shfl_xor(bd, off, 8);
        int   oi = __shfl_xor(bi, off, 8);
        if (od < bd || (od == bd && oi < bi)) { bd = od; bi = oi; }
    }
    if (l3 == 0)
        keys[m] = ((unsigned long long)__float_as_uint(bd) << 32) | (unsigned)(bi & 2047);
}

// ======== fallback path (R5): used only if ws_size is too small ========
__global__ __launch_bounds__(256) void init_keys_kernel(unsigned long long* __restrict__ keys) {
    keys[blockIdx.x * 256 + threadIdx.x] = ~0ULL;
}

__global__ __launch_bounds__(256, 4) void dist_kernel(const float* __restrict__ x,
                                                      const float* __restrict__ cb,
                                                      const float* __restrict__ xsq,
                                                      const float* __restrict__ esq,
                                                      unsigned long long* __restrict__ keys) {
    __shared__ float As[16][128];
    __shared__ float Bs[16][132];
    int blk = blockIdx.x;
    int nt = blk & 15, mt = blk >> 4;
    int m0 = mt << 7;
    int b = m0 >> 11, t0 = m0 & (TLEN - 1);
    int n0 = nt << 7;
    int tid = threadIdx.x;
    int tm = tid >> 4, tn = tid & 15;
    const float* xbase = x + (size_t)b * DIM * TLEN + t0;
    float acc[8][8] = {};
    for (int kk = 0; kk < DIM; kk += 16) {
#pragma unroll
        for (int h = 0; h < 2; ++h) {
            int qq = tid + (h << 8);
            int k = qq >> 5, mq = (qq & 31) << 2;
            float4 v = *reinterpret_cast<const float4*>(xbase + (size_t)(kk + k) * TLEN + mq);
            *reinterpret_cast<float4*>(&As[k][mq]) = v;
        }
#pragma unroll
        for (int h = 0; h < 2; ++h) {
            int qq = tid + (h << 8);
            int nr = qq >> 2, kc = (qq & 3) << 2;
            float4 v = *reinterpret_cast<const float4*>(cb + (size_t)(n0 + nr) * DIM + kk + kc);
            Bs[kc + 0][nr] = v.x; Bs[kc + 1][nr] = v.y;
            Bs[kc + 2][nr] = v.z; Bs[kc + 3][nr] = v.w;
        }
        __syncthreads();
#pragma unroll
        for (int k = 0; k < 16; ++k) {
            float4 a0 = *reinterpret_cast<const float4*>(&As[k][tm << 2]);
            float4 a1 = *reinterpret_cast<const float4*>(&As[k][64 + (tm << 2)]);
            float4 b0 = *reinterpret_cast<const float4*>(&Bs[k][tn << 2]);
            float4 b1 = *reinterpret_cast<const float4*>(&Bs[k][64 + (tn << 2)]);
            float am[8] = {a0.x, a0.y, a0.z, a0.w, a1.x, a1.y, a1.z, a1.w};
            float bn[8] = {b0.x, b0.y, b0.z, b0.w, b1.x, b1.y, b1.z, b1.w};
#pragma unroll
            for (int mi = 0; mi < 8; ++mi)
#pragma unroll
                for (int ni = 0; ni < 8; ++ni)
                    acc[mi][ni] = fmaf(am[mi], bn[ni], acc[mi][ni]);
        }
        __syncthreads();
    }
    int cn[8]; float es[8];
#pragma unroll
    for (int ni = 0; ni < 8; ++ni) {
        cn[ni] = n0 + ((ni < 4) ? (tn << 2) + ni : 60 + (tn << 2) + ni);
        es[ni] = esq[cn[ni]];
    }
#pragma unroll
    for (int mi = 0; mi < 8; ++mi) {
        int m = m0 + ((mi < 4) ? (tm << 2) + mi : 60 + (tm << 2) + mi);
        float xs = xsq[m];
        float bd = 3.4e38f;
        int bi = 0x7fffffff;
#pragma unroll
        for (int ni = 0; ni < 8; ++ni) {
            float d2 = __fadd_rn(__fadd_rn(xs, -2.0f * acc[mi][ni]), es[ni]);
            if (d2 < bd) { bd = d2; bi = cn[ni]; }
        }
        for (int off = 1; off < 16; off <<= 1) {
            float od = __shfl_xor(bd, off, 16);
            int oi = __shfl_xor(bi, off, 16);
            if (od < bd || (od == bd && oi < bi)) { bd = od; bi = oi; }
        }
        if (tn == 0) {
            unsigned long long key =
                ((unsigned long long)__float_as_uint(bd) << 32) | (unsigned)(bi & 2047);
            atomicMin(&keys[m], key);
        }
    }
}
// ======== end fallback ========

// ---- gather + STE output + idx + per-block loss sums (c-oct 32B cb gather).
// bsum groups (b, c, t/256) and their shfl-tree order reproduced exactly.
__global__ __launch_bounds__(256) void gather_kernel(const float* __restrict__ x,
                                                     const float* __restrict__ cb,
                                                     const unsigned long long* __restrict__ keys,
                                                     float* __restrict__ out,
                                                     float* __restrict__ bsum) {
    int tid = threadIdx.x;
    int blk = blockIdx.x;               // 4096 = 16 b x 8 tc x 32 c8
    int c8 = blk & 31, tc = (blk >> 5) & 7, b = blk >> 8;
    int c0 = c8 << 3;
    int t = (tc << 8) + tid;
    int m = (b << 11) + t;
    unsigned idx = (unsigned)(keys[m]) & 2047u;
    const float* crow = cb + (size_t)idx * DIM + c0;
    float4 cv0 = *reinterpret_cast<const float4*>(crow);
    float4 cv1 = *reinterpret_cast<const float4*>(crow + 4);
    if (c8 == 0) out[(size_t)IDX_OFF + m] = (float)idx;

    float qv[8] = {cv0.x, cv0.y, cv0.z, cv0.w, cv1.x, cv1.y, cv1.z, cv1.w};
    __shared__ float wsum[4][8];
    int lane = tid & 63, wid = tid >> 6;
    float sv[8];
#pragma unroll
    for (int cc = 0; cc < 8; ++cc) {
        size_t e = (size_t)b * (DIM * TLEN) + (size_t)(c0 + cc) * TLEN + t;
        float xv = x[e];
        float diff = __fsub_rn(qv[cc], xv);
        out[e] = __fadd_rn(xv, diff);
        float s = __fmul_rn(diff, diff);
        for (int off = 32; off > 0; off >>= 1) s += __shfl_down(s, off, 64);
        sv[cc] = s;
    }
    if (lane == 0) {
#pragma unroll
        for (int cc = 0; cc < 8; ++cc) wsum[wid][cc] = sv[cc];
    }
    __syncthreads();
    if (tid == 0) {
#pragma unroll
        for (int cc = 0; cc < 8; ++cc)
            bsum[(b << 11) + ((c0 + cc) << 3) + tc] =
                ((wsum[0][cc] + wsum[1][cc]) + (wsum[2][cc] + wsum[3][cc]));
    }
}

__global__ __launch_bounds__(1024) void finalize_kernel(const float* __restrict__ bsum,
                                                        float* __restrict__ out) {
    double s = 0.0;
    for (int i = threadIdx.x; i < 32768; i += 1024) s += (double)bsum[i];
    for (int off = 32; off > 0; off >>= 1) s += __shfl_down(s, off, 64);
    __shared__ double wsum[16];
    int lane = threadIdx.x & 63, wid = threadIdx.x >> 6;
    if (lane == 0) wsum[wid] = s;
    __syncthreads();
    if (threadIdx.x == 0) {
        double total = 0.0;
        for (int ww = 0; ww < 16; ++ww) total += wsum[ww];
        float mean = (float)(total / (double)NELEM);
        out[LOSS_OFF] = mean;
        out[LOSS_OFF + 1] = 0.25f * mean;
    }
}

extern "C" void kernel_launch(void* const* d_in, const int* in_sizes, int n_in,
                              void* d_out, int out_size, void* d_ws, size_t ws_size,
                              hipStream_t stream) {
    const float* x  = (const float*)d_in[0];
    const float* cb = (const float*)d_in[1];
    float* out = (float*)d_out;
    char* ws = (char*)d_ws;
    float* xsq = (float*)(ws + OFF_XSQ);
    float* esq = (float*)(ws + OFF_ESQ);
    unsigned long long* keys = (unsigned long long*)(ws + OFF_KEYS);
    float* bsum = (float*)(ws + OFF_BSUM);

    if (ws_size >= WS_NEED) {
        __hip_bfloat16* Ehi = (__hip_bfloat16*)(ws + OFF_EHI);
        int* ccnt  = (int*)(ws + OFF_CCNT);
        int* clist = (int*)(ws + OFF_CLIST);
        prep_e_kernel<<<KCODES / 4, 256, 0, stream>>>(cb, Ehi, esq);
        dist_cand_kernel<<<NROWS / 64, 256, 0, stream>>>(x, Ehi, esq, ccnt, clist);
        recheck_kernel<<<NROWS / 32, 256, 0, stream>>>(x, cb, esq, ccnt, clist, keys);
    } else {
        esq_kernel<<<KCODES / 256, 256, 0, stream>>>(cb, esq);
        xsq_kernel<<<NROWS / 256, 256, 0, stream>>>(x, xsq);
        init_keys_kernel<<<NROWS / 256, 256, 0, stream>>>(keys);
        dist_kernel<<<(NROWS / 128) * (KCODES / 128), 256, 0, stream>>>(x, cb, xsq, esq, keys);
    }
    gather_kernel<<<(NB * 8 * 32), 256, 0, stream>>>(x, cb, keys, out, bsum);
    finalize_kernel<<<1, 1024, 0, stream>>>(bsum, out);
}

// Round 5
// 218.989 us; speedup vs baseline: 3.4285x; 3.4285x over previous
//
#include <hip/hip_runtime.h>
#include <hip/hip_bf16.h>

// Problem constants
#define KCODES 2048
#define DIM 256
#define TLEN 2048
#define NB 16
#define NROWS (NB * TLEN)          // 32768 rows (b*t)
#define NELEM (NB * DIM * TLEN)    // 8388608 elements of x / quant
#define LOSS_OFF NELEM
#define IDX_OFF (NELEM + 2)

// Margin in the a = (bf16 dot) domain. s = xsq - 2a + esq; argmin s == argmax of
// (a - esq/2). Filter on a alone with margin covering: 2*bf16-err (s-domain 3e-3
// proven in R8 => a-domain 1.5e-3) + esq spread/2 (~3e-5) + u16-trunc of stored
// maxima (~1.2e-4). 1.8e-3 > sum => candidate superset provably contains argmin.
#define AMARGIN 1.8e-3f

// Candidate list capacity per row. Retrospective global-max qualification gives
// E[#cands] ~ 3-8; overflow still handled exactly by full-scan fallback.
#define CCAP 48

// ws layout (bytes) — total ~8.0 MB
#define OFF_XSQ   0ull                       // 131072 (fallback path only)
#define OFF_ESQ   131072ull                  // 8192
#define OFF_KEYS  139264ull                  // 262144
#define OFF_BSUM  401408ull                  // 131072
#define OFF_EHI   532480ull                  // 1048576
#define OFF_CCNT  1581056ull                 // 131072
#define OFF_CLIST 1712128ull                 // 32768*48*4 = 6291456
#define WS_NEED   8003584ull

typedef __bf16 bf16x8 __attribute__((ext_vector_type(8)));
typedef float  f32x4  __attribute__((ext_vector_type(4)));
typedef int    i32x4  __attribute__((ext_vector_type(4)));

__device__ __forceinline__ float sq_rn(float v) { return __fmul_rn(v, v); }

// order-preserving float<->u32 encoding (uint order == float order)
__device__ __forceinline__ unsigned encf(float f) {
    unsigned u = __float_as_uint(f);
    return (u & 0x80000000u) ? ~u : (u | 0x80000000u);
}
__device__ __forceinline__ float decf(unsigned k) {
    return __uint_as_float((k & 0x80000000u) ? (k & 0x7FFFFFFFu) : ~k);
}

// ---- x_sq: numpy pairwise sum (fallback path only)
__global__ __launch_bounds__(256) void xsq_kernel(const float* __restrict__ x,
                                                  float* __restrict__ xsq) {
    int m = blockIdx.x * 256 + threadIdx.x;
    int b = m >> 11, t = m & (TLEN - 1);
    const float* p = x + (size_t)b * DIM * TLEN + t;
    float h[2];
#pragma unroll
    for (int half = 0; half < 2; ++half) {
        int c0 = half * 128;
        float r[8];
#pragma unroll
        for (int j = 0; j < 8; ++j) r[j] = sq_rn(p[(size_t)(c0 + j) * TLEN]);
        for (int i = 8; i < 128; i += 8) {
#pragma unroll
            for (int j = 0; j < 8; ++j)
                r[j] = __fadd_rn(r[j], sq_rn(p[(size_t)(c0 + i + j) * TLEN]));
        }
        h[half] = __fadd_rn(__fadd_rn(__fadd_rn(r[0], r[1]), __fadd_rn(r[2], r[3])),
                            __fadd_rn(__fadd_rn(r[4], r[5]), __fadd_rn(r[6], r[7])));
    }
    xsq[m] = __fadd_rn(h[0], h[1]);
}

// ---- esq standalone (fallback path only)
__global__ __launch_bounds__(256) void esq_kernel(const float* __restrict__ cb,
                                                  float* __restrict__ esq) {
    int k = blockIdx.x * 256 + threadIdx.x;
    const float* p = cb + (size_t)k * DIM;
    float h[2];
#pragma unroll
    for (int half = 0; half < 2; ++half) {
        int c0 = half * 128;
        float r[8];
#pragma unroll
        for (int j = 0; j < 8; ++j) r[j] = sq_rn(p[c0 + j]);
        for (int i = 8; i < 128; i += 8) {
#pragma unroll
            for (int j = 0; j < 8; ++j)
                r[j] = __fadd_rn(r[j], sq_rn(p[c0 + i + j]));
        }
        h[half] = __fadd_rn(__fadd_rn(__fadd_rn(r[0], r[1]), __fadd_rn(r[2], r[3])),
                            __fadd_rn(__fadd_rn(r[4], r[5]), __fadd_rn(r[6], r[7])));
    }
    esq[k] = __fadd_rn(h[0], h[1]);
}

// ---- fused prep: cb -> Ehi (bf16) + esq (exact np pairwise chain, bit-identical)
__global__ __launch_bounds__(256) void prep_e_kernel(const float* __restrict__ cb,
                                                     __hip_bfloat16* __restrict__ Ehi,
                                                     float* __restrict__ esq) {
    int tid = threadIdx.x;
    int w = tid >> 6, lane = tid & 63;
    int k = (blockIdx.x << 2) + w;          // code row
    const float* p = cb + (size_t)k * DIM;

    float4 v = *reinterpret_cast<const float4*>(p + (lane << 2));
    alignas(8) __hip_bfloat16 h4[4];
    h4[0] = __float2bfloat16(v.x); h4[1] = __float2bfloat16(v.y);
    h4[2] = __float2bfloat16(v.z); h4[3] = __float2bfloat16(v.w);
    *reinterpret_cast<int2*>(Ehi + (size_t)k * DIM + (lane << 2)) = *reinterpret_cast<int2*>(h4);

    if (lane < 16) {
        int c0 = (lane >> 3) << 7, j = lane & 7;
        float r = sq_rn(p[c0 + j]);
        for (int i = 8; i < 128; i += 8)
            r = __fadd_rn(r, sq_rn(p[c0 + i + j]));
        float a  = __fadd_rn(r,  __shfl_xor(r, 1, 16));
        float b2 = __fadd_rn(a,  __shfl_xor(a, 2, 16));
        float h  = __fadd_rn(b2, __shfl_xor(b2, 4, 16));
        float tot = __fadd_rn(h, __shfl_xor(h, 8, 16));   // h0 + h1, own-first
        if (lane == 0) esq[k] = tot;
    }
}

// ---- stage one [64 codes][64 k] bf16 chunk (8KB) of Ehi into LDS.
// chunk s: nt = s>>3 (128-code tile), half = (s>>2)&1, kc = s&3 (k offset).
// Wave w stages (and later reads) ONLY rows w*16..w*16+15 of the chunk ->
// barrier-free. Pre-swizzled-source XOR (read side XORs (c&7)<<4).
__device__ __forceinline__ void stage_chunk(const __hip_bfloat16* __restrict__ Ehi,
                                            __hip_bfloat16* dstbase,
                                            int s, int w, int srow, int scol) {
    int ntq = s >> 3, half = (s >> 2) & 1, kc = s & 3;
    const __hip_bfloat16* gsrc =
        Ehi + (size_t)((ntq << 7) + (half << 6) + (w << 4) + srow) * DIM + (kc << 6) + scol;
#pragma unroll
    for (int j = 0; j < 2; ++j)
        __builtin_amdgcn_global_load_lds(
            (const __attribute__((address_space(1))) unsigned int*)(gsrc + (size_t)(j << 3) * DIM),
            (__attribute__((address_space(3))) unsigned int*)(dstbase + (((w << 4) + (j << 3)) << 6)),
            16, 0, 0);
}

// ---- Phase A: 64 rows/block, all 2048 codes, barrier-free 3-buffer ring with
// counted vmcnt(4) (depth 2). A-frags loaded ONCE and PINNED in VGPRs via asm
// (R3/R4 lesson: compiler silently rematerialized them -> VGPR_Count 124 and
// ~1.6k cy/chunk of hidden reload; pin makes that impossible). RETROSPECTIVE
// filter: per-(row, 32-code subtile) (wmax-u16, margin-mask) in padded LDS
// (strides 66/65 -> conflict-free); post-loop expansion vs global max.
__global__ __launch_bounds__(256, 2) void dist_cand_kernel(const float* __restrict__ x,
                                                           const __hip_bfloat16* __restrict__ Ehi,
                                                           int* __restrict__ ccnt_g,
                                                           int* __restrict__ clist_g) {
    __shared__ __hip_bfloat16 Bh[3][64 * 64];      // 24 KB ring of 8KB chunks
    __shared__ unsigned short wmax16_s[64][66];    // 8.25 KB, stride 33 dw (odd)
    __shared__ unsigned mask_s[64][65];            // 16.25 KB, stride 65 dw (odd)
    __shared__ int ccnt_s[64];                     // 256 B

    int tid = threadIdx.x;
    int w = tid >> 6, lane = tid & 63;
    int q = lane >> 4, c = lane & 15;
    int swzc = (c & 7) << 4;
    int blk = blockIdx.x;                           // 512 blocks, 64 rows each
    int b = blk >> 5;
    int t0 = (blk << 6) & (TLEN - 1);
    const float* xb = x + (size_t)b * DIM * TLEN + t0;

    if (tid < 64) ccnt_s[tid] = 0;

    // A-frags: xf[mi][kh]: row t0 + mi*16 + c, k = kh*32 + q*8 + j. Loaded once,
    // packed to i32x4, PINNED (opaque to rematerialization).
    i32x4 xf[4][8];
#pragma unroll
    for (int mi = 0; mi < 4; ++mi) {
        int t = (mi << 4) + c;
#pragma unroll
        for (int kh = 0; kh < 8; ++kh) {
            union { __hip_bfloat16 h[8]; i32x4 v; } u;
#pragma unroll
            for (int j = 0; j < 8; ++j)
                u.h[j] = __float2bfloat16(xb[(size_t)((kh << 5) + (q << 3) + j) * TLEN + t]);
            xf[mi][kh] = u.v;
            asm volatile("" : "+v"(xf[mi][kh]));
        }
    }

    f32x4 acc[2][4];
#pragma unroll
    for (int ci = 0; ci < 2; ++ci)
#pragma unroll
        for (int mi = 0; mi < 4; ++mi) acc[ci][mi] = (f32x4){0.f, 0.f, 0.f, 0.f};

    int srow = lane >> 3;
    int scol = ((lane & 7) ^ srow) << 3;

    // drain xf loads so in-loop vmcnt counts ONLY stage loads (2/chunk/thread)
    asm volatile("s_waitcnt vmcnt(0)" ::: "memory");

    stage_chunk(Ehi, &Bh[0][0], 0, w, srow, scol);
    stage_chunk(Ehi, &Bh[1][0], 1, w, srow, scol);

    int cur = 0;                                   // buffer of chunk s
#pragma unroll 1
    for (int nt = 0; nt < 16; ++nt) {
#pragma unroll
        for (int hk = 0; hk < 8; ++hk) {
            int s = (nt << 3) + hk;
            int half = (hk >> 2) & 1;              // compile-time under unroll
            // guard: my ds_reads from the buffer being re-staged are done
            asm volatile("s_waitcnt lgkmcnt(0)" ::: "memory");
            int sb = cur == 0 ? 2 : cur - 1;       // (s+2)%3 == (s-1)%3
            if (s + 2 < 128) stage_chunk(Ehi, &Bh[sb][0], s + 2, w, srow, scol);
            if (s < 126) asm volatile("s_waitcnt vmcnt(4)" ::: "memory");
            else         asm volatile("s_waitcnt vmcnt(0)" ::: "memory");

            const char* basep = reinterpret_cast<const char*>(&Bh[cur][0]);
            int rowbyte = ((w << 4) + c) << 7;
#pragma unroll
            for (int kh = 0; kh < 2; ++kh) {
                int swz = ((kh << 6) | (q << 4)) ^ swzc;
                bf16x8 cf = *reinterpret_cast<const bf16x8*>(basep + rowbyte + swz);
#pragma unroll
                for (int mi = 0; mi < 4; ++mi) {
                    bf16x8 af = __builtin_bit_cast(bf16x8, xf[mi][((hk & 3) << 1) | kh]);
                    acc[half][mi] = __builtin_amdgcn_mfma_f32_16x16x32_bf16(cf, af, acc[half][mi], 0, 0, 0);
                }
            }
            cur = cur == 2 ? 0 : cur + 1;
        }

        // per-nt epilogue: per-(row, wave-subtile) max + margin mask -> LDS.
#pragma unroll
        for (int mi = 0; mi < 4; ++mi) {
            int r = (mi << 4) + c;
            float a8[8];
#pragma unroll
            for (int ci = 0; ci < 2; ++ci)
#pragma unroll
                for (int reg = 0; reg < 4; ++reg)
                    a8[ci * 4 + reg] = acc[ci][mi][reg];
            float m01 = fmaxf(fmaxf(a8[0], a8[1]), fmaxf(a8[2], a8[3]));
            float m23 = fmaxf(fmaxf(a8[4], a8[5]), fmaxf(a8[6], a8[7]));
            float wmax = fmaxf(m01, m23);
            wmax = fmaxf(wmax, __shfl_xor(wmax, 16, 64));
            wmax = fmaxf(wmax, __shfl_xor(wmax, 32, 64));
            float thrw = wmax - AMARGIN;
            unsigned bits = 0;
#pragma unroll
            for (int v = 0; v < 8; ++v)
                if (a8[v] >= thrw)
                    bits |= 1u << (((v >> 2) << 4) | (q << 2) | (v & 3));
            bits |= (unsigned)__shfl_xor((int)bits, 16, 64);
            bits |= (unsigned)__shfl_xor((int)bits, 32, 64);
            if (q == 0) {
                int st = (nt << 2) | w;
                wmax16_s[r][st] = (unsigned short)(encf(wmax) >> 16);  // trunc-down
                mask_s[r][st] = bits;
            }
            acc[0][mi] = (f32x4){0.f, 0.f, 0.f, 0.f};
            acc[1][mi] = (f32x4){0.f, 0.f, 0.f, 0.f};
        }
    }

    __syncthreads();

    // Expansion: retrospective global-max qualification -> compact lists.
    {
        int r = tid >> 2, j4 = tid & 3;
        int m = (blk << 6) + r;
        int g16 = 0;                                // < any encf>>16
#pragma unroll
        for (int i = 0; i < 16; ++i) {
            int v = wmax16_s[r][(i << 2) | j4];
            g16 = v > g16 ? v : g16;
        }
        g16 = max(g16, __shfl_xor(g16, 1, 4));
        g16 = max(g16, __shfl_xor(g16, 2, 4));
        float thr = decf((unsigned)g16 << 16) - AMARGIN;
        for (int i = 0; i < 16; ++i) {
            int st = (i << 2) | j4;
            if (decf((unsigned)wmax16_s[r][st] << 16) >= thr) {
                unsigned bits = mask_s[r][st];
                while (bits) {
                    int p = __ffs(bits) - 1; bits &= bits - 1;
                    int pos = atomicAdd(&ccnt_s[r], 1);
                    if (pos < CCAP)
                        clist_g[(size_t)m * CCAP + pos] =
                            ((st >> 2) << 7) + (((p >> 4)) << 6) + ((st & 3) << 4) + (p & 15);
                }
            }
        }
    }
    __syncthreads();
    if ((tid & 3) == 0) ccnt_g[(blk << 6) + (tid >> 2)] = ccnt_s[tid >> 2];
}

// ---- Phase B: exact recheck over candidate lists (xs computed in-kernel with
// the exact np pairwise chain). Full-scan fallback on overflow keeps exactness
// unconditional.
__global__ __launch_bounds__(256) void recheck_kernel(const float* __restrict__ x,
                                                      const float* __restrict__ cb,
                                                      const float* __restrict__ esq,
                                                      const int* __restrict__ ccnt,
                                                      const int* __restrict__ clist,
                                                      unsigned long long* __restrict__ keys) {
    __shared__ float xT[DIM * 33];

    int tid = threadIdx.x;
    int blk = blockIdx.x;               // 1024 blocks, 32 rows each
    int b = blk >> 6, t0 = (blk & 63) << 5;
    const float* xb = x + (size_t)b * DIM * TLEN + t0;

    {   // coalesced staging: 8 c-rows x 32 t per iter
        int tl = tid & 31, c8 = tid >> 5;
        for (int cc = 0; cc < 32; ++cc) {
            int c = (cc << 3) + c8;
            xT[c * 33 + tl] = xb[(size_t)c * TLEN + tl];
        }
    }
    __syncthreads();

    int g = tid >> 3, l3 = tid & 7;     // group g handles row t0+g
    int m = (b << 11) + t0 + g;

    // xs: np pairwise chain, bit-exact (lane l3 owns accumulator r[l3])
    float h[2];
#pragma unroll
    for (int half = 0; half < 2; ++half) {
        int c0 = half * 128;
        float r = sq_rn(xT[(c0 + l3) * 33 + g]);
        for (int i = 8; i < 128; i += 8)
            r = __fadd_rn(r, sq_rn(xT[(c0 + i + l3) * 33 + g]));
        float a = __fadd_rn(r, __shfl_xor(r, 1, 8));
        float bb = __fadd_rn(a, __shfl_xor(a, 2, 8));
        h[half] = __fadd_rn(bb, __shfl_xor(bb, 4, 8));
    }
    float xs = __fadd_rn(h[0], h[1]);

    int cnt = ccnt[m];
    float bd = 3.4e38f; int bi = 0x7fffffff;

    if (cnt <= CCAP) {
        for (int j = l3; j < cnt; j += 8) {
            int n = clist[(size_t)m * CCAP + j];
            const float* crow = cb + (size_t)n * DIM;
            float d = 0.f;
            for (int k = 0; k < DIM; k += 4) {     // ascending-k fmaf chain == np mm
                float4 cv = *reinterpret_cast<const float4*>(crow + k);
                d = fmaf(xT[(k + 0) * 33 + g], cv.x, d);
                d = fmaf(xT[(k + 1) * 33 + g], cv.y, d);
                d = fmaf(xT[(k + 2) * 33 + g], cv.z, d);
                d = fmaf(xT[(k + 3) * 33 + g], cv.w, d);
            }
            float d2 = __fadd_rn(__fadd_rn(xs, -2.0f * d), esq[n]);
            if (d2 < bd || (d2 == bd && n < bi)) { bd = d2; bi = n; }
        }
    } else {
        for (int n = l3; n < KCODES; n += 8) {
            const float* crow = cb + (size_t)n * DIM;
            float d = 0.f;
            for (int k = 0; k < DIM; k += 4) {
                float4 cv = *reinterpret_cast<const float4*>(crow + k);
                d = fmaf(xT[(k + 0) * 33 + g], cv.x, d);
                d = fmaf(xT[(k + 1) * 33 + g], cv.y, d);
                d = fmaf(xT[(k + 2) * 33 + g], cv.z, d);
                d = fmaf(xT[(k + 3) * 33 + g], cv.w, d);
            }
            float d2 = __fadd_rn(__fadd_rn(xs, -2.0f * d), esq[n]);
            if (d2 < bd || (d2 == bd && n < bi)) { bd = d2; bi = n; }
        }
    }
    for (int off = 1; off < 8; off <<= 1) {
        float od = __shfl_xor(bd, off, 8);
        int   oi = __shfl_xor(bi, off, 8);
        if (od < bd || (od == bd && oi < bi)) { bd = od; bi = oi; }
    }
    if (l3 == 0)
        keys[m] = ((unsigned long long)__float_as_uint(bd) << 32) | (unsigned)(bi & 2047);
}

// ======== fallback path (R5): used only if ws_size is too small ========
__global__ __launch_bounds__(256) void init_keys_kernel(unsigned long long* __restrict__ keys) {
    keys[blockIdx.x * 256 + threadIdx.x] = ~0ULL;
}

__global__ __launch_bounds__(256, 4) void dist_kernel(const float* __restrict__ x,
                                                      const float* __restrict__ cb,
                                                      const float* __restrict__ xsq,
                                                      const float* __restrict__ esq,
                                                      unsigned long long* __restrict__ keys) {
    __shared__ float As[16][128];
    __shared__ float Bs[16][132];
    int blk = blockIdx.x;
    int nt = blk & 15, mt = blk >> 4;
    int m0 = mt << 7;
    int b = m0 >> 11, t0 = m0 & (TLEN - 1);
    int n0 = nt << 7;
    int tid = threadIdx.x;
    int tm = tid >> 4, tn = tid & 15;
    const float* xbase = x + (size_t)b * DIM * TLEN + t0;
    float acc[8][8] = {};
    for (int kk = 0; kk < DIM; kk += 16) {
#pragma unroll
        for (int h = 0; h < 2; ++h) {
            int qq = tid + (h << 8);
            int k = qq >> 5, mq = (qq & 31) << 2;
            float4 v = *reinterpret_cast<const float4*>(xbase + (size_t)(kk + k) * TLEN + mq);
            *reinterpret_cast<float4*>(&As[k][mq]) = v;
        }
#pragma unroll
        for (int h = 0; h < 2; ++h) {
            int qq = tid + (h << 8);
            int nr = qq >> 2, kc = (qq & 3) << 2;
            float4 v = *reinterpret_cast<const float4*>(cb + (size_t)(n0 + nr) * DIM + kk + kc);
            Bs[kc + 0][nr] = v.x; Bs[kc + 1][nr] = v.y;
            Bs[kc + 2][nr] = v.z; Bs[kc + 3][nr] = v.w;
        }
        __syncthreads();
#pragma unroll
        for (int k = 0; k < 16; ++k) {
            float4 a0 = *reinterpret_cast<const float4*>(&As[k][tm << 2]);
            float4 a1 = *reinterpret_cast<const float4*>(&As[k][64 + (tm << 2)]);
            float4 b0 = *reinterpret_cast<const float4*>(&Bs[k][tn << 2]);
            float4 b1 = *reinterpret_cast<const float4*>(&Bs[k][64 + (tn << 2)]);
            float am[8] = {a0.x, a0.y, a0.z, a0.w, a1.x, a1.y, a1.z, a1.w};
            float bn[8] = {b0.x, b0.y, b0.z, b0.w, b1.x, b1.y, b1.z, b1.w};
#pragma unroll
            for (int mi = 0; mi < 8; ++mi)
#pragma unroll
                for (int ni = 0; ni < 8; ++ni)
                    acc[mi][ni] = fmaf(am[mi], bn[ni], acc[mi][ni]);
        }
        __syncthreads();
    }
    int cn[8]; float es[8];
#pragma unroll
    for (int ni = 0; ni < 8; ++ni) {
        cn[ni] = n0 + ((ni < 4) ? (tn << 2) + ni : 60 + (tn << 2) + ni);
        es[ni] = esq[cn[ni]];
    }
#pragma unroll
    for (int mi = 0; mi < 8; ++mi) {
        int m = m0 + ((mi < 4) ? (tm << 2) + mi : 60 + (tm << 2) + mi);
        float xs = xsq[m];
        float bd = 3.4e38f;
        int bi = 0x7fffffff;
#pragma unroll
        for (int ni = 0; ni < 8; ++ni) {
            float d2 = __fadd_rn(__fadd_rn(xs, -2.0f * acc[mi][ni]), es[ni]);
            if (d2 < bd) { bd = d2; bi = cn[ni]; }
        }
        for (int off = 1; off < 16; off <<= 1) {
            float od = __shfl_xor(bd, off, 16);
            int oi = __shfl_xor(bi, off, 16);
            if (od < bd || (od == bd && oi < bi)) { bd = od; bi = oi; }
        }
        if (tn == 0) {
            unsigned long long key =
                ((unsigned long long)__float_as_uint(bd) << 32) | (unsigned)(bi & 2047);
            atomicMin(&keys[m], key);
        }
    }
}
// ======== end fallback ========

// ---- gather + STE output + idx + per-block loss sums (c-oct 32B cb gather)
__global__ __launch_bounds__(256) void gather_kernel(const float* __restrict__ x,
                                                     const float* __restrict__ cb,
                                                     const unsigned long long* __restrict__ keys,
                                                     float* __restrict__ out,
                                                     float* __restrict__ bsum) {
    int tid = threadIdx.x;
    int blk = blockIdx.x;               // 4096 = 16 b x 8 tc x 32 c8
    int c8 = blk & 31, tc = (blk >> 5) & 7, b = blk >> 8;
    int c0 = c8 << 3;
    int t = (tc << 8) + tid;
    int m = (b << 11) + t;
    unsigned idx = (unsigned)(keys[m]) & 2047u;
    const float* crow = cb + (size_t)idx * DIM + c0;
    float4 cv0 = *reinterpret_cast<const float4*>(crow);
    float4 cv1 = *reinterpret_cast<const float4*>(crow + 4);
    if (c8 == 0) out[(size_t)IDX_OFF + m] = (float)idx;

    float qv[8] = {cv0.x, cv0.y, cv0.z, cv0.w, cv1.x, cv1.y, cv1.z, cv1.w};
    __shared__ float wsum[4][8];
    int lane = tid & 63, wid = tid >> 6;
    float sv[8];
#pragma unroll
    for (int cc = 0; cc < 8; ++cc) {
        size_t e = (size_t)b * (DIM * TLEN) + (size_t)(c0 + cc) * TLEN + t;
        float xv = x[e];
        float diff = __fsub_rn(qv[cc], xv);
        out[e] = __fadd_rn(xv, diff);
        float s = __fmul_rn(diff, diff);
        for (int off = 32; off > 0; off >>= 1) s += __shfl_down(s, off, 64);
        sv[cc] = s;
    }
    if (lane == 0) {
#pragma unroll
        for (int cc = 0; cc < 8; ++cc) wsum[wid][cc] = sv[cc];
    }
    __syncthreads();
    if (tid == 0) {
#pragma unroll
        for (int cc = 0; cc < 8; ++cc)
            bsum[(b << 11) + ((c0 + cc) << 3) + tc] =
                ((wsum[0][cc] + wsum[1][cc]) + (wsum[2][cc] + wsum[3][cc]));
    }
}

__global__ __launch_bounds__(1024) void finalize_kernel(const float* __restrict__ bsum,
                                                        float* __restrict__ out) {
    double s = 0.0;
    for (int i = threadIdx.x; i < 32768; i += 1024) s += (double)bsum[i];
    for (int off = 32; off > 0; off >>= 1) s += __shfl_down(s, off, 64);
    __shared__ double wsum[16];
    int lane = threadIdx.x & 63, wid = threadIdx.x >> 6;
    if (lane == 0) wsum[wid] = s;
    __syncthreads();
    if (threadIdx.x == 0) {
        double total = 0.0;
        for (int ww = 0; ww < 16; ++ww) total += wsum[ww];
        float mean = (float)(total / (double)NELEM);
        out[LOSS_OFF] = mean;
        out[LOSS_OFF + 1] = 0.25f * mean;
    }
}

extern "C" void kernel_launch(void* const* d_in, const int* in_sizes, int n_in,
                              void* d_out, int out_size, void* d_ws, size_t ws_size,
                              hipStream_t stream) {
    const float* x  = (const float*)d_in[0];
    const float* cb = (const float*)d_in[1];
    float* out = (float*)d_out;
    char* ws = (char*)d_ws;
    float* xsq = (float*)(ws + OFF_XSQ);
    float* esq = (float*)(ws + OFF_ESQ);
    unsigned long long* keys = (unsigned long long*)(ws + OFF_KEYS);
    float* bsum = (float*)(ws + OFF_BSUM);

    if (ws_size >= WS_NEED) {
        __hip_bfloat16* Ehi = (__hip_bfloat16*)(ws + OFF_EHI);
        int* ccnt  = (int*)(ws + OFF_CCNT);
        int* clist = (int*)(ws + OFF_CLIST);
        prep_e_kernel<<<KCODES / 4, 256, 0, stream>>>(cb, Ehi, esq);
        dist_cand_kernel<<<NROWS / 64, 256, 0, stream>>>(x, Ehi, ccnt, clist);
        recheck_kernel<<<NROWS / 32, 256, 0, stream>>>(x, cb, esq, ccnt, clist, keys);
    } else {
        esq_kernel<<<KCODES / 256, 256, 0, stream>>>(cb, esq);
        xsq_kernel<<<NROWS / 256, 256, 0, stream>>>(x, xsq);
        init_keys_kernel<<<NROWS / 256, 256, 0, stream>>>(keys);
        dist_kernel<<<(NROWS / 128) * (KCODES / 128), 256, 0, stream>>>(x, cb, xsq, esq, keys);
    }
    gather_kernel<<<(NB * 8 * 32), 256, 0, stream>>>(x, cb, keys, out, bsum);
    finalize_kernel<<<1, 1024, 0, stream>>>(bsum, out);
}

// Round 6
// 207.532 us; speedup vs baseline: 3.6178x; 1.0552x over previous
//
#include <hip/hip_runtime.h>
#include <hip/hip_bf16.h>

// Problem constants
#define KCODES 2048
#define DIM 256
#define TLEN 2048
#define NB 16
#define NROWS (NB * TLEN)          // 32768 rows (b*t)
#define NELEM (NB * DIM * TLEN)    // 8388608 elements of x / quant
#define LOSS_OFF NELEM
#define IDX_OFF (NELEM + 2)

// Margin in the a = (bf16 dot) domain. s = xsq - 2a + esq; argmin s == argmax of
// (a - esq/2). Filter on a alone with margin covering: 2*bf16-err (s-domain 3e-3
// proven in R8 => a-domain 1.5e-3) + esq spread/2 (~3e-5) + u16-trunc of stored
// maxima (~1.2e-4). 1.8e-3 > sum => candidate superset provably contains argmin.
#define AMARGIN 1.8e-3f

// Candidate list capacity per row. Retrospective global-max qualification gives
// E[#cands] ~ 3-8; overflow still handled exactly by full-scan fallback.
#define CCAP 48

// ws layout (bytes) — total ~8.0 MB
#define OFF_XSQ   0ull                       // 131072 (fallback path only)
#define OFF_ESQ   131072ull                  // 8192
#define OFF_KEYS  139264ull                  // 262144
#define OFF_BSUM  401408ull                  // 131072
#define OFF_EHI   532480ull                  // 1048576
#define OFF_CCNT  1581056ull                 // 131072
#define OFF_CLIST 1712128ull                 // 32768*48*4 = 6291456
#define WS_NEED   8003584ull

typedef __bf16 bf16x8 __attribute__((ext_vector_type(8)));
typedef float  f32x4  __attribute__((ext_vector_type(4)));
typedef int    i32x4  __attribute__((ext_vector_type(4)));

__device__ __forceinline__ float sq_rn(float v) { return __fmul_rn(v, v); }

// order-preserving float<->u32 encoding (uint order == float order)
__device__ __forceinline__ unsigned encf(float f) {
    unsigned u = __float_as_uint(f);
    return (u & 0x80000000u) ? ~u : (u | 0x80000000u);
}
__device__ __forceinline__ float decf(unsigned k) {
    return __uint_as_float((k & 0x80000000u) ? (k & 0x7FFFFFFFu) : ~k);
}

// ---- x_sq: numpy pairwise sum (fallback path only)
__global__ __launch_bounds__(256) void xsq_kernel(const float* __restrict__ x,
                                                  float* __restrict__ xsq) {
    int m = blockIdx.x * 256 + threadIdx.x;
    int b = m >> 11, t = m & (TLEN - 1);
    const float* p = x + (size_t)b * DIM * TLEN + t;
    float h[2];
#pragma unroll
    for (int half = 0; half < 2; ++half) {
        int c0 = half * 128;
        float r[8];
#pragma unroll
        for (int j = 0; j < 8; ++j) r[j] = sq_rn(p[(size_t)(c0 + j) * TLEN]);
        for (int i = 8; i < 128; i += 8) {
#pragma unroll
            for (int j = 0; j < 8; ++j)
                r[j] = __fadd_rn(r[j], sq_rn(p[(size_t)(c0 + i + j) * TLEN]));
        }
        h[half] = __fadd_rn(__fadd_rn(__fadd_rn(r[0], r[1]), __fadd_rn(r[2], r[3])),
                            __fadd_rn(__fadd_rn(r[4], r[5]), __fadd_rn(r[6], r[7])));
    }
    xsq[m] = __fadd_rn(h[0], h[1]);
}

// ---- esq standalone (fallback path only)
__global__ __launch_bounds__(256) void esq_kernel(const float* __restrict__ cb,
                                                  float* __restrict__ esq) {
    int k = blockIdx.x * 256 + threadIdx.x;
    const float* p = cb + (size_t)k * DIM;
    float h[2];
#pragma unroll
    for (int half = 0; half < 2; ++half) {
        int c0 = half * 128;
        float r[8];
#pragma unroll
        for (int j = 0; j < 8; ++j) r[j] = sq_rn(p[c0 + j]);
        for (int i = 8; i < 128; i += 8) {
#pragma unroll
            for (int j = 0; j < 8; ++j)
                r[j] = __fadd_rn(r[j], sq_rn(p[c0 + i + j]));
        }
        h[half] = __fadd_rn(__fadd_rn(__fadd_rn(r[0], r[1]), __fadd_rn(r[2], r[3])),
                            __fadd_rn(__fadd_rn(r[4], r[5]), __fadd_rn(r[6], r[7])));
    }
    esq[k] = __fadd_rn(h[0], h[1]);
}

// ---- fused prep: cb -> Ehi (bf16) + esq (exact np pairwise chain, bit-identical)
__global__ __launch_bounds__(256) void prep_e_kernel(const float* __restrict__ cb,
                                                     __hip_bfloat16* __restrict__ Ehi,
                                                     float* __restrict__ esq) {
    int tid = threadIdx.x;
    int w = tid >> 6, lane = tid & 63;
    int k = (blockIdx.x << 2) + w;          // code row
    const float* p = cb + (size_t)k * DIM;

    float4 v = *reinterpret_cast<const float4*>(p + (lane << 2));
    alignas(8) __hip_bfloat16 h4[4];
    h4[0] = __float2bfloat16(v.x); h4[1] = __float2bfloat16(v.y);
    h4[2] = __float2bfloat16(v.z); h4[3] = __float2bfloat16(v.w);
    *reinterpret_cast<int2*>(Ehi + (size_t)k * DIM + (lane << 2)) = *reinterpret_cast<int2*>(h4);

    if (lane < 16) {
        int c0 = (lane >> 3) << 7, j = lane & 7;
        float r = sq_rn(p[c0 + j]);
        for (int i = 8; i < 128; i += 8)
            r = __fadd_rn(r, sq_rn(p[c0 + i + j]));
        float a  = __fadd_rn(r,  __shfl_xor(r, 1, 16));
        float b2 = __fadd_rn(a,  __shfl_xor(a, 2, 16));
        float h  = __fadd_rn(b2, __shfl_xor(b2, 4, 16));
        float tot = __fadd_rn(h, __shfl_xor(h, 8, 16));   // h0 + h1, own-first
        if (lane == 0) esq[k] = tot;
    }
}

// ---- stage one [64 codes][64 k] bf16 chunk (8KB) of Ehi into LDS.
// chunk s: nt = s>>3 (128-code tile), half = (s>>2)&1, kc = s&3 (k offset).
// Wave w stages (and later reads) ONLY rows w*16..w*16+15 of the chunk ->
// barrier-free. Pre-swizzled-source XOR (read side XORs (c&7)<<4).
__device__ __forceinline__ void stage_chunk(const __hip_bfloat16* __restrict__ Ehi,
                                            __hip_bfloat16* dstbase,
                                            int s, int w, int srow, int scol) {
    int ntq = s >> 3, half = (s >> 2) & 1, kc = s & 3;
    const __hip_bfloat16* gsrc =
        Ehi + (size_t)((ntq << 7) + (half << 6) + (w << 4) + srow) * DIM + (kc << 6) + scol;
#pragma unroll
    for (int j = 0; j < 2; ++j)
        __builtin_amdgcn_global_load_lds(
            (const __attribute__((address_space(1))) unsigned int*)(gsrc + (size_t)(j << 3) * DIM),
            (__attribute__((address_space(3))) unsigned int*)(dstbase + (((w << 4) + (j << 3)) << 6)),
            16, 0, 0);
}

// ---- Phase A: 32 rows/block (R5 post-mortem: 64-row xf = 128 VGPR forced a
// spill — scratch reloads are VMEM, breaking both the register theory AND the
// counted-vmcnt pipeline). 32 rows -> xf = 64 VGPR, total ~115 <= 128 cap
// (launch_bounds(256,4)) -> 16 waves/CU AND truly resident A-frags. Grid 1024,
// 3-buffer ring, counted vmcnt(4), barrier-free (wave-exclusive chunk rows).
// RETROSPECTIVE filter unchanged: per-(row, 32-code subtile) u16-max + mask in
// padded LDS; post-loop expansion vs global max.
__global__ __launch_bounds__(256, 4) void dist_cand_kernel(const float* __restrict__ x,
                                                           const __hip_bfloat16* __restrict__ Ehi,
                                                           int* __restrict__ ccnt_g,
                                                           int* __restrict__ clist_g) {
    __shared__ __hip_bfloat16 Bh[3][64 * 64];      // 24 KB ring of 8KB chunks
    __shared__ unsigned short wmax16_s[32][66];    // 4.1 KB, stride 33 dw (odd)
    __shared__ unsigned mask_s[32][65];            // 8.1 KB, stride 65 dw (odd)
    __shared__ int ccnt_s[32];                     // 128 B

    int tid = threadIdx.x;
    int w = tid >> 6, lane = tid & 63;
    int q = lane >> 4, c = lane & 15;
    int swzc = (c & 7) << 4;
    int blk = blockIdx.x;                           // 1024 blocks, 32 rows each
    int b = blk >> 6;
    int t0 = (blk & 63) << 5;
    const float* xb = x + (size_t)b * DIM * TLEN + t0;

    if (tid < 32) ccnt_s[tid] = 0;

    // A-frags: xf[mi][kh]: row t0 + mi*16 + c, k = kh*32 + q*8 + j. Loaded once,
    // packed to i32x4, pinned (opaque to rematerialization). 64 VGPR total.
    i32x4 xf[2][8];
#pragma unroll
    for (int mi = 0; mi < 2; ++mi) {
        int t = (mi << 4) + c;
#pragma unroll
        for (int kh = 0; kh < 8; ++kh) {
            union { __hip_bfloat16 h[8]; i32x4 v; } u;
#pragma unroll
            for (int j = 0; j < 8; ++j)
                u.h[j] = __float2bfloat16(xb[(size_t)((kh << 5) + (q << 3) + j) * TLEN + t]);
            xf[mi][kh] = u.v;
            asm volatile("" : "+v"(xf[mi][kh]));
        }
    }

    f32x4 acc[2][2];
#pragma unroll
    for (int ci = 0; ci < 2; ++ci)
#pragma unroll
        for (int mi = 0; mi < 2; ++mi) acc[ci][mi] = (f32x4){0.f, 0.f, 0.f, 0.f};

    int srow = lane >> 3;
    int scol = ((lane & 7) ^ srow) << 3;

    // drain xf loads so in-loop vmcnt counts ONLY stage loads (2/chunk/thread)
    asm volatile("s_waitcnt vmcnt(0)" ::: "memory");

    stage_chunk(Ehi, &Bh[0][0], 0, w, srow, scol);
    stage_chunk(Ehi, &Bh[1][0], 1, w, srow, scol);

    int cur = 0;                                   // buffer of chunk s
#pragma unroll 1
    for (int nt = 0; nt < 16; ++nt) {
#pragma unroll
        for (int hk = 0; hk < 8; ++hk) {
            int s = (nt << 3) + hk;
            int half = (hk >> 2) & 1;              // compile-time under unroll
            // guard: my ds_reads from the buffer being re-staged are done
            asm volatile("s_waitcnt lgkmcnt(0)" ::: "memory");
            int sb = cur == 0 ? 2 : cur - 1;       // (s+2)%3 == (s-1)%3
            if (s + 2 < 128) stage_chunk(Ehi, &Bh[sb][0], s + 2, w, srow, scol);
            if (s < 126) asm volatile("s_waitcnt vmcnt(4)" ::: "memory");
            else         asm volatile("s_waitcnt vmcnt(0)" ::: "memory");

            const char* basep = reinterpret_cast<const char*>(&Bh[cur][0]);
            int rowbyte = ((w << 4) + c) << 7;
#pragma unroll
            for (int kh = 0; kh < 2; ++kh) {
                int swz = ((kh << 6) | (q << 4)) ^ swzc;
                bf16x8 cf = *reinterpret_cast<const bf16x8*>(basep + rowbyte + swz);
#pragma unroll
                for (int mi = 0; mi < 2; ++mi) {
                    bf16x8 af = __builtin_bit_cast(bf16x8, xf[mi][((hk & 3) << 1) | kh]);
                    acc[half][mi] = __builtin_amdgcn_mfma_f32_16x16x32_bf16(cf, af, acc[half][mi], 0, 0, 0);
                }
            }
            cur = cur == 2 ? 0 : cur + 1;
        }

        // per-nt epilogue: per-(row, wave-subtile) max + margin mask -> LDS.
#pragma unroll
        for (int mi = 0; mi < 2; ++mi) {
            int r = (mi << 4) + c;
            float a8[8];
#pragma unroll
            for (int ci = 0; ci < 2; ++ci)
#pragma unroll
                for (int reg = 0; reg < 4; ++reg)
                    a8[ci * 4 + reg] = acc[ci][mi][reg];
            float m01 = fmaxf(fmaxf(a8[0], a8[1]), fmaxf(a8[2], a8[3]));
            float m23 = fmaxf(fmaxf(a8[4], a8[5]), fmaxf(a8[6], a8[7]));
            float wmax = fmaxf(m01, m23);
            wmax = fmaxf(wmax, __shfl_xor(wmax, 16, 64));
            wmax = fmaxf(wmax, __shfl_xor(wmax, 32, 64));
            float thrw = wmax - AMARGIN;
            unsigned bits = 0;
#pragma unroll
            for (int v = 0; v < 8; ++v)
                if (a8[v] >= thrw)
                    bits |= 1u << (((v >> 2) << 4) | (q << 2) | (v & 3));
            bits |= (unsigned)__shfl_xor((int)bits, 16, 64);
            bits |= (unsigned)__shfl_xor((int)bits, 32, 64);
            if (q == 0) {
                int st = (nt << 2) | w;
                wmax16_s[r][st] = (unsigned short)(encf(wmax) >> 16);  // trunc-down
                mask_s[r][st] = bits;
            }
            acc[0][mi] = (f32x4){0.f, 0.f, 0.f, 0.f};
            acc[1][mi] = (f32x4){0.f, 0.f, 0.f, 0.f};
        }
    }

    __syncthreads();

    // Expansion: retrospective global-max qualification -> compact lists.
    {
        int r = tid >> 3, j8 = tid & 7;
        int m = (blk << 5) + r;
        int g16 = 0;                                // < any encf>>16
#pragma unroll
        for (int i = 0; i < 8; ++i) {
            int v = wmax16_s[r][(i << 3) | j8];
            g16 = v > g16 ? v : g16;
        }
        g16 = max(g16, __shfl_xor(g16, 1, 8));
        g16 = max(g16, __shfl_xor(g16, 2, 8));
        g16 = max(g16, __shfl_xor(g16, 4, 8));
        float thr = decf((unsigned)g16 << 16) - AMARGIN;
        for (int i = 0; i < 8; ++i) {
            int st = (i << 3) | j8;
            if (decf((unsigned)wmax16_s[r][st] << 16) >= thr) {
                unsigned bits = mask_s[r][st];
                while (bits) {
                    int p = __ffs(bits) - 1; bits &= bits - 1;
                    int pos = atomicAdd(&ccnt_s[r], 1);
                    if (pos < CCAP)
                        clist_g[(size_t)m * CCAP + pos] =
                            ((st >> 2) << 7) + (((p >> 4)) << 6) + ((st & 3) << 4) + (p & 15);
                }
            }
        }
    }
    __syncthreads();
    if ((tid & 7) == 0) ccnt_g[(blk << 5) + (tid >> 3)] = ccnt_s[tid >> 3];
}

// ---- Phase B: exact recheck over candidate lists (xs computed in-kernel with
// the exact np pairwise chain). Full-scan fallback on overflow keeps exactness
// unconditional.
__global__ __launch_bounds__(256) void recheck_kernel(const float* __restrict__ x,
                                                      const float* __restrict__ cb,
                                                      const float* __restrict__ esq,
                                                      const int* __restrict__ ccnt,
                                                      const int* __restrict__ clist,
                                                      unsigned long long* __restrict__ keys) {
    __shared__ float xT[DIM * 33];

    int tid = threadIdx.x;
    int blk = blockIdx.x;               // 1024 blocks, 32 rows each
    int b = blk >> 6, t0 = (blk & 63) << 5;
    const float* xb = x + (size_t)b * DIM * TLEN + t0;

    {   // coalesced staging: 8 c-rows x 32 t per iter
        int tl = tid & 31, c8 = tid >> 5;
        for (int cc = 0; cc < 32; ++cc) {
            int c = (cc << 3) + c8;
            xT[c * 33 + tl] = xb[(size_t)c * TLEN + tl];
        }
    }
    __syncthreads();

    int g = tid >> 3, l3 = tid & 7;     // group g handles row t0+g
    int m = (b << 11) + t0 + g;

    // xs: np pairwise chain, bit-exact (lane l3 owns accumulator r[l3])
    float h[2];
#pragma unroll
    for (int half = 0; half < 2; ++half) {
        int c0 = half * 128;
        float r = sq_rn(xT[(c0 + l3) * 33 + g]);
        for (int i = 8; i < 128; i += 8)
            r = __fadd_rn(r, sq_rn(xT[(c0 + i + l3) * 33 + g]));
        float a = __fadd_rn(r, __shfl_xor(r, 1, 8));
        float bb = __fadd_rn(a, __shfl_xor(a, 2, 8));
        h[half] = __fadd_rn(bb, __shfl_xor(bb, 4, 8));
    }
    float xs = __fadd_rn(h[0], h[1]);

    int cnt = ccnt[m];
    float bd = 3.4e38f; int bi = 0x7fffffff;

    if (cnt <= CCAP) {
        for (int j = l3; j < cnt; j += 8) {
            int n = clist[(size_t)m * CCAP + j];
            const float* crow = cb + (size_t)n * DIM;
            float d = 0.f;
            for (int k = 0; k < DIM; k += 4) {     // ascending-k fmaf chain == np mm
                float4 cv = *reinterpret_cast<const float4*>(crow + k);
                d = fmaf(xT[(k + 0) * 33 + g], cv.x, d);
                d = fmaf(xT[(k + 1) * 33 + g], cv.y, d);
                d = fmaf(xT[(k + 2) * 33 + g], cv.z, d);
                d = fmaf(xT[(k + 3) * 33 + g], cv.w, d);
            }
            float d2 = __fadd_rn(__fadd_rn(xs, -2.0f * d), esq[n]);
            if (d2 < bd || (d2 == bd && n < bi)) { bd = d2; bi = n; }
        }
    } else {
        for (int n = l3; n < KCODES; n += 8) {
            const float* crow = cb + (size_t)n * DIM;
            float d = 0.f;
            for (int k = 0; k < DIM; k += 4) {
                float4 cv = *reinterpret_cast<const float4*>(crow + k);
                d = fmaf(xT[(k + 0) * 33 + g], cv.x, d);
                d = fmaf(xT[(k + 1) * 33 + g], cv.y, d);
                d = fmaf(xT[(k + 2) * 33 + g], cv.z, d);
                d = fmaf(xT[(k + 3) * 33 + g], cv.w, d);
            }
            float d2 = __fadd_rn(__fadd_rn(xs, -2.0f * d), esq[n]);
            if (d2 < bd || (d2 == bd && n < bi)) { bd = d2; bi = n; }
        }
    }
    for (int off = 1; off < 8; off <<= 1) {
        float od = __shfl_xor(bd, off, 8);
        int   oi = __shfl_xor(bi, off, 8);
        if (od < bd || (od == bd && oi < bi)) { bd = od; bi = oi; }
    }
    if (l3 == 0)
        keys[m] = ((unsigned long long)__float_as_uint(bd) << 32) | (unsigned)(bi & 2047);
}

// ======== fallback path (R5): used only if ws_size is too small ========
__global__ __launch_bounds__(256) void init_keys_kernel(unsigned long long* __restrict__ keys) {
    keys[blockIdx.x * 256 + threadIdx.x] = ~0ULL;
}

__global__ __launch_bounds__(256, 4) void dist_kernel(const float* __restrict__ x,
                                                      const float* __restrict__ cb,
                                                      const float* __restrict__ xsq,
                                                      const float* __restrict__ esq,
                                                      unsigned long long* __restrict__ keys) {
    __shared__ float As[16][128];
    __shared__ float Bs[16][132];
    int blk = blockIdx.x;
    int nt = blk & 15, mt = blk >> 4;
    int m0 = mt << 7;
    int b = m0 >> 11, t0 = m0 & (TLEN - 1);
    int n0 = nt << 7;
    int tid = threadIdx.x;
    int tm = tid >> 4, tn = tid & 15;
    const float* xbase = x + (size_t)b * DIM * TLEN + t0;
    float acc[8][8] = {};
    for (int kk = 0; kk < DIM; kk += 16) {
#pragma unroll
        for (int h = 0; h < 2; ++h) {
            int qq = tid + (h << 8);
            int k = qq >> 5, mq = (qq & 31) << 2;
            float4 v = *reinterpret_cast<const float4*>(xbase + (size_t)(kk + k) * TLEN + mq);
            *reinterpret_cast<float4*>(&As[k][mq]) = v;
        }
#pragma unroll
        for (int h = 0; h < 2; ++h) {
            int qq = tid + (h << 8);
            int nr = qq >> 2, kc = (qq & 3) << 2;
            float4 v = *reinterpret_cast<const float4*>(cb + (size_t)(n0 + nr) * DIM + kk + kc);
            Bs[kc + 0][nr] = v.x; Bs[kc + 1][nr] = v.y;
            Bs[kc + 2][nr] = v.z; Bs[kc + 3][nr] = v.w;
        }
        __syncthreads();
#pragma unroll
        for (int k = 0; k < 16; ++k) {
            float4 a0 = *reinterpret_cast<const float4*>(&As[k][tm << 2]);
            float4 a1 = *reinterpret_cast<const float4*>(&As[k][64 + (tm << 2)]);
            float4 b0 = *reinterpret_cast<const float4*>(&Bs[k][tn << 2]);
            float4 b1 = *reinterpret_cast<const float4*>(&Bs[k][64 + (tn << 2)]);
            float am[8] = {a0.x, a0.y, a0.z, a0.w, a1.x, a1.y, a1.z, a1.w};
            float bn[8] = {b0.x, b0.y, b0.z, b0.w, b1.x, b1.y, b1.z, b1.w};
#pragma unroll
            for (int mi = 0; mi < 8; ++mi)
#pragma unroll
                for (int ni = 0; ni < 8; ++ni)
                    acc[mi][ni] = fmaf(am[mi], bn[ni], acc[mi][ni]);
        }
        __syncthreads();
    }
    int cn[8]; float es[8];
#pragma unroll
    for (int ni = 0; ni < 8; ++ni) {
        cn[ni] = n0 + ((ni < 4) ? (tn << 2) + ni : 60 + (tn << 2) + ni);
        es[ni] = esq[cn[ni]];
    }
#pragma unroll
    for (int mi = 0; mi < 8; ++mi) {
        int m = m0 + ((mi < 4) ? (tm << 2) + mi : 60 + (tm << 2) + mi);
        float xs = xsq[m];
        float bd = 3.4e38f;
        int bi = 0x7fffffff;
#pragma unroll
        for (int ni = 0; ni < 8; ++ni) {
            float d2 = __fadd_rn(__fadd_rn(xs, -2.0f * acc[mi][ni]), es[ni]);
            if (d2 < bd) { bd = d2; bi = cn[ni]; }
        }
        for (int off = 1; off < 16; off <<= 1) {
            float od = __shfl_xor(bd, off, 16);
            int oi = __shfl_xor(bi, off, 16);
            if (od < bd || (od == bd && oi < bi)) { bd = od; bi = oi; }
        }
        if (tn == 0) {
            unsigned long long key =
                ((unsigned long long)__float_as_uint(bd) << 32) | (unsigned)(bi & 2047);
            atomicMin(&keys[m], key);
        }
    }
}
// ======== end fallback ========

// ---- gather + STE output + idx + per-block loss sums (c-oct 32B cb gather)
__global__ __launch_bounds__(256) void gather_kernel(const float* __restrict__ x,
                                                     const float* __restrict__ cb,
                                                     const unsigned long long* __restrict__ keys,
                                                     float* __restrict__ out,
                                                     float* __restrict__ bsum) {
    int tid = threadIdx.x;
    int blk = blockIdx.x;               // 4096 = 16 b x 8 tc x 32 c8
    int c8 = blk & 31, tc = (blk >> 5) & 7, b = blk >> 8;
    int c0 = c8 << 3;
    int t = (tc << 8) + tid;
    int m = (b << 11) + t;
    unsigned idx = (unsigned)(keys[m]) & 2047u;
    const float* crow = cb + (size_t)idx * DIM + c0;
    float4 cv0 = *reinterpret_cast<const float4*>(crow);
    float4 cv1 = *reinterpret_cast<const float4*>(crow + 4);
    if (c8 == 0) out[(size_t)IDX_OFF + m] = (float)idx;

    float qv[8] = {cv0.x, cv0.y, cv0.z, cv0.w, cv1.x, cv1.y, cv1.z, cv1.w};
    __shared__ float wsum[4][8];
    int lane = tid & 63, wid = tid >> 6;
    float sv[8];
#pragma unroll
    for (int cc = 0; cc < 8; ++cc) {
        size_t e = (size_t)b * (DIM * TLEN) + (size_t)(c0 + cc) * TLEN + t;
        float xv = x[e];
        float diff = __fsub_rn(qv[cc], xv);
        out[e] = __fadd_rn(xv, diff);
        float s = __fmul_rn(diff, diff);
        for (int off = 32; off > 0; off >>= 1) s += __shfl_down(s, off, 64);
        sv[cc] = s;
    }
    if (lane == 0) {
#pragma unroll
        for (int cc = 0; cc < 8; ++cc) wsum[wid][cc] = sv[cc];
    }
    __syncthreads();
    if (tid == 0) {
#pragma unroll
        for (int cc = 0; cc < 8; ++cc)
            bsum[(b << 11) + ((c0 + cc) << 3) + tc] =
                ((wsum[0][cc] + wsum[1][cc]) + (wsum[2][cc] + wsum[3][cc]));
    }
}

__global__ __launch_bounds__(1024) void finalize_kernel(const float* __restrict__ bsum,
                                                        float* __restrict__ out) {
    double s = 0.0;
    for (int i = threadIdx.x; i < 32768; i += 1024) s += (double)bsum[i];
    for (int off = 32; off > 0; off >>= 1) s += __shfl_down(s, off, 64);
    __shared__ double wsum[16];
    int lane = threadIdx.x & 63, wid = threadIdx.x >> 6;
    if (lane == 0) wsum[wid] = s;
    __syncthreads();
    if (threadIdx.x == 0) {
        double total = 0.0;
        for (int ww = 0; ww < 16; ++ww) total += wsum[ww];
        float mean = (float)(total / (double)NELEM);
        out[LOSS_OFF] = mean;
        out[LOSS_OFF + 1] = 0.25f * mean;
    }
}

extern "C" void kernel_launch(void* const* d_in, const int* in_sizes, int n_in,
                              void* d_out, int out_size, void* d_ws, size_t ws_size,
                              hipStream_t stream) {
    const float* x  = (const float*)d_in[0];
    const float* cb = (const float*)d_in[1];
    float* out = (float*)d_out;
    char* ws = (char*)d_ws;
    float* xsq = (float*)(ws + OFF_XSQ);
    float* esq = (float*)(ws + OFF_ESQ);
    unsigned long long* keys = (unsigned long long*)(ws + OFF_KEYS);
    float* bsum = (float*)(ws + OFF_BSUM);

    if (ws_size >= WS_NEED) {
        __hip_bfloat16* Ehi = (__hip_bfloat16*)(ws + OFF_EHI);
        int* ccnt  = (int*)(ws + OFF_CCNT);
        int* clist = (int*)(ws + OFF_CLIST);
        prep_e_kernel<<<KCODES / 4, 256, 0, stream>>>(cb, Ehi, esq);
        dist_cand_kernel<<<NROWS / 32, 256, 0, stream>>>(x, Ehi, ccnt, clist);
        recheck_kernel<<<NROWS / 32, 256, 0, stream>>>(x, cb, esq, ccnt, clist, keys);
    } else {
        esq_kernel<<<KCODES / 256, 256, 0, stream>>>(cb, esq);
        xsq_kernel<<<NROWS / 256, 256, 0, stream>>>(x, xsq);
        init_keys_kernel<<<NROWS / 256, 256, 0, stream>>>(keys);
        dist_kernel<<<(NROWS / 128) * (KCODES / 128), 256, 0, stream>>>(x, cb, xsq, esq, keys);
    }
    gather_kernel<<<(NB * 8 * 32), 256, 0, stream>>>(x, cb, keys, out, bsum);
    finalize_kernel<<<1, 1024, 0, stream>>>(bsum, out);
}